// Round 14
// baseline (53.965 us; speedup 1.0000x reference)
//
#include <hip/hip_runtime.h>

#define BS 512
#define MARGIN 0.5f

using f32x4 = __attribute__((ext_vector_type(4))) float;

// K1: block b owns pos-space anchors {2b, 2b+1}. Fully self-contained:
//  - stage target to LDS; ballot-scan ranks (wave 0 writes rank/anchor ids)
//  - GEMV vs all of pred (fp32, thread-owns-row, L2-resident stream)
//  - finalize d-rows into compacted LDS arrays (j-role and k-role)
//  - hinge: readlane j-broadcast x register k, pure-VALU count
//  - plain psum/pcnt store. No atomics, no fences, no cross-block deps.
__global__ __launch_bounds__(256) void kpair(const float* __restrict__ pred,
                                             const int* __restrict__ target,
                                             float* __restrict__ psum,
                                             float* __restrict__ pcnt) {
    const int b = blockIdx.x;
    const int tid = threadIdx.x;
    const int lane = tid & 63;
    const int w = tid >> 6;

    __shared__ int tgs[BS];
    __shared__ int rnk[BS];            // pos-rank if target==1 else neg-rank
    __shared__ int ia_s[2];
    __shared__ float xa0[BS], xa1[BS];
    __shared__ float nrm[BS];
    __shared__ float djc0[BS], djc1[BS];   // compacted j-role (d+margin / -1e9)
    __shared__ float knc0[BS], knc1[BS];   // compacted k-role
    __shared__ float redS[4], redC[4];

    tgs[tid] = target[tid];
    tgs[tid + 256] = target[tid + 256];
    __syncthreads();

    // every wave scans (needs npos/nneg); wave 0 writes rank + anchor ids
    int pbase = 0, nbase = 0;
    const unsigned long long below = (1ULL << lane) - 1ULL;
#pragma unroll
    for (int c = 0; c < 8; ++c) {
        const int idx = c * 64 + lane;
        const int tg = tgs[idx];
        const unsigned long long mp = __ballot(tg == 1);
        if (w == 0) {
            const int prk = pbase + __popcll(mp & below);
            const int nrk = nbase + __popcll((~mp) & below);
            rnk[idx] = (tg == 1) ? prk : nrk;
            if (tg == 1 && prk == 2 * b) ia_s[0] = idx;
            if (tg == 1 && prk == 2 * b + 1) ia_s[1] = idx;
        }
        const int np = __popcll(mp);
        pbase += np;
        nbase += 64 - np;
    }
    const int npos = pbase;
    const int nneg = nbase;
    __syncthreads();

    if (2 * b >= npos) {  // uniform: inactive block
        if (tid == 0) { psum[b] = 0.f; pcnt[b] = 0.f; }
        return;
    }
    const bool has1 = (2 * b + 1) < npos;
    const int ia0 = ia_s[0];
    const int ia1 = has1 ? ia_s[1] : ia0;

    // stage the two anchor rows
    xa0[tid] = pred[ia0 * BS + tid];
    xa0[tid + 256] = pred[ia0 * BS + tid + 256];
    xa1[tid] = pred[ia1 * BS + tid];
    xa1[tid + 256] = pred[ia1 * BS + tid + 256];
    __syncthreads();

    // GEMV: thread owns rows tid and tid+256; fp32 dots + norms
    float dotA0 = 0.f, dotA1 = 0.f, nnA = 0.f;
    {
        const float* rp = pred + tid * BS;
#pragma unroll 4
        for (int e = 0; e < BS; e += 4) {
            const f32x4 v = *(const f32x4*)(rp + e);
            const f32x4 a = *(const f32x4*)(xa0 + e);
            const f32x4 c2 = *(const f32x4*)(xa1 + e);
#pragma unroll
            for (int j = 0; j < 4; ++j) {
                dotA0 = fmaf(v[j], a[j], dotA0);
                dotA1 = fmaf(v[j], c2[j], dotA1);
                nnA = fmaf(v[j], v[j], nnA);
            }
        }
    }
    nrm[tid] = nnA;
    float dotB0 = 0.f, dotB1 = 0.f, nnB = 0.f;
    {
        const float* rp = pred + (tid + 256) * BS;
#pragma unroll 4
        for (int e = 0; e < BS; e += 4) {
            const f32x4 v = *(const f32x4*)(rp + e);
            const f32x4 a = *(const f32x4*)(xa0 + e);
            const f32x4 c2 = *(const f32x4*)(xa1 + e);
#pragma unroll
            for (int j = 0; j < 4; ++j) {
                dotB0 = fmaf(v[j], a[j], dotB0);
                dotB1 = fmaf(v[j], c2[j], dotB1);
                nnB = fmaf(v[j], v[j], nnB);
            }
        }
    }
    nrm[tid + 256] = nnB;
    __syncthreads();

    const float ivA = 1.f / fmaxf(sqrtf(nrm[ia0]), 1e-10f);
    const float ivB = 1.f / fmaxf(sqrtf(nrm[ia1]), 1e-10f);

    // finalize row tid
    {
        const float ivr = 1.f / fmaxf(sqrtf(nnA), 1e-10f);
        const float d0 = sqrtf(fmaxf(2.f - 2.f * dotA0 * ivA * ivr, 0.f));
        const float d1 = sqrtf(fmaxf(2.f - 2.f * dotA1 * ivB * ivr, 0.f));
        const int tg = tgs[tid];
        const int rk = rnk[tid];
        if (tg == 1) {
            djc0[rk] = (tid == ia0) ? -1e9f : d0 + MARGIN;
            djc1[rk] = (tid == ia1) ? -1e9f : d1 + MARGIN;
        } else {
            knc0[rk] = d0;
            knc1[rk] = d1;
        }
    }
    // finalize row tid+256
    {
        const int r = tid + 256;
        const float ivr = 1.f / fmaxf(sqrtf(nnB), 1e-10f);
        const float d0 = sqrtf(fmaxf(2.f - 2.f * dotB0 * ivA * ivr, 0.f));
        const float d1 = sqrtf(fmaxf(2.f - 2.f * dotB1 * ivB * ivr, 0.f));
        const int tg = tgs[r];
        const int rk = rnk[r];
        if (tg == 1) {
            djc0[rk] = (r == ia0) ? -1e9f : d0 + MARGIN;
            djc1[rk] = (r == ia1) ? -1e9f : d1 + MARGIN;
        } else {
            knc0[rk] = d0;
            knc1[rk] = d1;
        }
    }
    const int npad = (npos + 63) & ~63;
    for (int p = npos + tid; p < npad; p += 256) {
        djc0[p] = -1e9f;
        djc1[p] = -1e9f;
    }
    __syncthreads();

    // hinge: thread's k-value(s) in registers; j broadcast via readlane
    const float kv0 = (tid < nneg) ? knc0[tid] : 1e30f;
    const float kv1 = (tid < nneg) ? knc1[tid] : 1e30f;
    float sum0 = 0.f, sum1 = 0.f, cnt0 = 0.f, cnt1 = 0.f;
    const int nc = npad >> 6;
    for (int c = 0; c < nc; ++c) {
        const float jA = djc0[c * 64 + lane];
        const float jB = djc1[c * 64 + lane];
#pragma unroll 16
        for (int jj = 0; jj < 64; ++jj) {
            const float tA = __int_as_float(
                __builtin_amdgcn_readlane(__float_as_int(jA), jj));
            const float tB = __int_as_float(
                __builtin_amdgcn_readlane(__float_as_int(jB), jj));
            const float v0 = tA - kv0;
            const float v1 = tB - kv1;
            sum0 += fmaxf(v0, 0.f);
            cnt0 += (v0 > 0.f) ? 1.f : 0.f;
            sum1 += fmaxf(v1, 0.f);
            cnt1 += (v1 > 0.f) ? 1.f : 0.f;
        }
    }
    if (nneg > 256) {  // uniform rare path: second k-slot
        const float kv0b = (tid + 256 < nneg) ? knc0[tid + 256] : 1e30f;
        const float kv1b = (tid + 256 < nneg) ? knc1[tid + 256] : 1e30f;
        for (int c = 0; c < nc; ++c) {
            const float jA = djc0[c * 64 + lane];
            const float jB = djc1[c * 64 + lane];
#pragma unroll 16
            for (int jj = 0; jj < 64; ++jj) {
                const float tA = __int_as_float(
                    __builtin_amdgcn_readlane(__float_as_int(jA), jj));
                const float tB = __int_as_float(
                    __builtin_amdgcn_readlane(__float_as_int(jB), jj));
                const float v0 = tA - kv0b;
                const float v1 = tB - kv1b;
                sum0 += fmaxf(v0, 0.f);
                cnt0 += (v0 > 0.f) ? 1.f : 0.f;
                sum1 += fmaxf(v1, 0.f);
                cnt1 += (v1 > 0.f) ? 1.f : 0.f;
            }
        }
    }
    if (!has1) { sum1 = 0.f; cnt1 = 0.f; }  // anchor-1 duplicate guard

    float s = sum0 + sum1;
    float c = cnt0 + cnt1;
#pragma unroll
    for (int o = 32; o > 0; o >>= 1) {
        s += __shfl_xor(s, o, 64);
        c += __shfl_xor(c, o, 64);
    }
    if (lane == 0) { redS[w] = s; redC[w] = c; }
    __syncthreads();
    if (tid == 0) {
        psum[b] = (redS[0] + redS[1]) + (redS[2] + redS[3]);
        pcnt[b] = (redC[0] + redC[1]) + (redC[2] + redC[3]);
    }
}

// K2: one wave reduces 256 partials, writes out. Fixed order, deterministic.
__global__ __launch_bounds__(64) void kfin(const float* __restrict__ psum,
                                           const float* __restrict__ pcnt,
                                           float* __restrict__ out) {
    const int lane = threadIdx.x;
    float s = 0.f, c = 0.f;
#pragma unroll
    for (int r = 0; r < 4; ++r) {
        s += psum[r * 64 + lane];
        c += pcnt[r * 64 + lane];
    }
#pragma unroll
    for (int o = 32; o > 0; o >>= 1) {
        s += __shfl_xor(s, o, 64);
        c += __shfl_xor(c, o, 64);
    }
    if (lane == 0) out[0] = s / (c + 1e-7f);
}

extern "C" void kernel_launch(void* const* d_in, const int* in_sizes, int n_in,
                              void* d_out, int out_size, void* d_ws, size_t ws_size,
                              hipStream_t stream) {
    const float* pred = (const float*)d_in[0];
    const int* target = (const int*)d_in[1];
    float* out = (float*)d_out;
    char* base = (char*)d_ws;

    float* psum = (float*)base;              // 256 floats
    float* pcnt = (float*)(base + 1024);     // 256 floats

    kpair<<<256, 256, 0, stream>>>(pred, target, psum, pcnt);
    kfin<<<1, 64, 0, stream>>>(psum, pcnt, out);
}

// Round 15
// 39.850 us; speedup vs baseline: 1.3542x; 1.3542x over previous
//
#include <hip/hip_runtime.h>
#include <hip/hip_bf16.h>

#define BS 512
#define MARGIN 0.5f

using short8 = __attribute__((ext_vector_type(8))) short;
using f32x4 = __attribute__((ext_vector_type(4))) float;

__device__ inline short bf16_rne(float x) {
    __hip_bfloat16 h = __float2bfloat16(x);
    return *(short*)&h;
}

// Kernel 0: one wave. Stable compaction of positive / negative indices.
__global__ __launch_bounds__(64) void ksetup(const int* __restrict__ target,
                                             int* __restrict__ plist,
                                             int* __restrict__ nlist,
                                             int* __restrict__ counts) {
    const int lane = threadIdx.x;
    int pbase = 0, nbase = 0;
#pragma unroll
    for (int c = 0; c < 8; ++c) {
        const int idx = c * 64 + lane;
        const int t = target[idx];
        const unsigned long long mp = __ballot(t == 1);
        const unsigned long long mn = __ballot(t == 0);
        const unsigned long long below = (1ULL << lane) - 1ULL;
        if (t == 1) plist[pbase + __popcll(mp & below)] = idx;
        else        nlist[nbase + __popcll(mn & below)] = idx;
        pbase += __popcll(mp);
        nbase += __popcll(mn);
    }
    if (lane == 0) { counts[0] = pbase; counts[1] = nbase; }
}

// Kernel 1: dist_c[b][j] for POSITIVE anchors only (rows in pos-space), all cols.
// One wave per 32x32 tile; fused normalize (norms in-wave); bf16 MFMA dots.
__global__ __launch_bounds__(64) void kdistf(const float* __restrict__ pred,
                                             const int* __restrict__ plist,
                                             const int* __restrict__ counts,
                                             float* __restrict__ dist) {
    const int npos = counts[0];
    const int r0 = blockIdx.y * 32;
    if (r0 >= npos) return;
    const int lane = threadIdx.x;
    const int c0 = blockIdx.x * 32;
    const int rl = lane & 15;
    const int koff = (lane >> 4) * 8;

    const int pr0 = min(r0 + rl, npos - 1);
    const int pr1 = min(r0 + 16 + rl, npos - 1);
    const float* A0 = pred + plist[pr0] * BS;
    const float* A1 = pred + plist[pr1] * BS;
    const float* B0 = pred + (c0 + rl) * BS;
    const float* B1 = pred + (c0 + 16 + rl) * BS;

    f32x4 acc00 = {0.f, 0.f, 0.f, 0.f};
    f32x4 acc01 = {0.f, 0.f, 0.f, 0.f};
    f32x4 acc10 = {0.f, 0.f, 0.f, 0.f};
    f32x4 acc11 = {0.f, 0.f, 0.f, 0.f};
    float na0 = 0.f, na1 = 0.f, nb0 = 0.f, nb1 = 0.f;

#pragma unroll 4
    for (int ks = 0; ks < 16; ++ks) {
        const int k = ks * 32 + koff;
        const f32x4 a0l = *(const f32x4*)(A0 + k);
        const f32x4 a0h = *(const f32x4*)(A0 + k + 4);
        const f32x4 a1l = *(const f32x4*)(A1 + k);
        const f32x4 a1h = *(const f32x4*)(A1 + k + 4);
        const f32x4 b0l = *(const f32x4*)(B0 + k);
        const f32x4 b0h = *(const f32x4*)(B0 + k + 4);
        const f32x4 b1l = *(const f32x4*)(B1 + k);
        const f32x4 b1h = *(const f32x4*)(B1 + k + 4);

        short8 sa0, sa1, sb0, sb1;
#pragma unroll
        for (int j = 0; j < 4; ++j) {
            na0 += a0l[j] * a0l[j] + a0h[j] * a0h[j];
            na1 += a1l[j] * a1l[j] + a1h[j] * a1h[j];
            nb0 += b0l[j] * b0l[j] + b0h[j] * b0h[j];
            nb1 += b1l[j] * b1l[j] + b1h[j] * b1h[j];
            sa0[j] = bf16_rne(a0l[j]); sa0[4 + j] = bf16_rne(a0h[j]);
            sa1[j] = bf16_rne(a1l[j]); sa1[4 + j] = bf16_rne(a1h[j]);
            sb0[j] = bf16_rne(b0l[j]); sb0[4 + j] = bf16_rne(b0h[j]);
            sb1[j] = bf16_rne(b1l[j]); sb1[4 + j] = bf16_rne(b1h[j]);
        }
        acc00 = __builtin_amdgcn_mfma_f32_16x16x32_bf16(sa0, sb0, acc00, 0, 0, 0);
        acc01 = __builtin_amdgcn_mfma_f32_16x16x32_bf16(sa0, sb1, acc01, 0, 0, 0);
        acc10 = __builtin_amdgcn_mfma_f32_16x16x32_bf16(sa1, sb0, acc10, 0, 0, 0);
        acc11 = __builtin_amdgcn_mfma_f32_16x16x32_bf16(sa1, sb1, acc11, 0, 0, 0);
    }

    na0 += __shfl_xor(na0, 16, 64); na0 += __shfl_xor(na0, 32, 64);
    na1 += __shfl_xor(na1, 16, 64); na1 += __shfl_xor(na1, 32, 64);
    nb0 += __shfl_xor(nb0, 16, 64); nb0 += __shfl_xor(nb0, 32, 64);
    nb1 += __shfl_xor(nb1, 16, 64); nb1 += __shfl_xor(nb1, 32, 64);
    const float ia0 = 1.0f / fmaxf(sqrtf(na0), 1e-10f);
    const float ia1 = 1.0f / fmaxf(sqrtf(na1), 1e-10f);
    const float ib0 = 1.0f / fmaxf(sqrtf(nb0), 1e-10f);
    const float ib1 = 1.0f / fmaxf(sqrtf(nb1), 1e-10f);

    // C/D layout: col = lane&15, row = (lane>>4)*4 + reg  [m89]
    const int rbase = (lane >> 4) * 4;
#pragma unroll
    for (int fr = 0; fr < 2; ++fr) {
        const float iaSel = (fr == 0) ? ia0 : ia1;
#pragma unroll
        for (int fc = 0; fc < 2; ++fc) {
            f32x4 v = (fr == 0) ? (fc == 0 ? acc00 : acc01) : (fc == 0 ? acc10 : acc11);
            const int col = c0 + fc * 16 + rl;
            const float icol = (fc == 0) ? ib0 : ib1;
#pragma unroll
            for (int r = 0; r < 4; ++r) {
                const float irow = __shfl(iaSel, rbase + r, 64);
                const int rowp = r0 + fr * 16 + rbase + r;  // pos-space row
                float d2 = 2.0f - 2.0f * v[r] * irow * icol;
                dist[rowp * BS + col] = sqrtf(fmaxf(d2, 0.f));
            }
        }
    }
}

// Kernel 2: block b = pos-space anchor. j over compacted positives (readlane
// broadcast), k = thread's compacted negative(s). Plain psum/pcnt stores.
__global__ __launch_bounds__(256) void ktriplet(const float* __restrict__ dist,
                                                const int* __restrict__ plist,
                                                const int* __restrict__ nlist,
                                                const int* __restrict__ counts,
                                                float* __restrict__ psum,
                                                float* __restrict__ pcnt) {
    const int b = blockIdx.x;
    const int tid = threadIdx.x;
    const int npos = counts[0];
    if (b >= npos) {
        if (tid == 0) { psum[b] = 0.f; pcnt[b] = 0.f; }
        return;
    }
    const int nneg = counts[1];
    const int lane = tid & 63;
    const int w = tid >> 6;
    __shared__ float sbuf[4];
    __shared__ float cbuf[4];

    const float* drow = dist + b * BS;

    const float bv0 = (tid < nneg) ? drow[nlist[tid]] : 1e30f;
    const float bv1 = (tid + 256 < nneg) ? drow[nlist[tid + 256]] : 1e30f;

    const int ja = w * 64 + lane;
    const int jb = (w + 4) * 64 + lane;
    const float av0 = (ja < npos && ja != b) ? drow[plist[ja]] + MARGIN : -1e9f;
    const float av1 = (jb < npos && jb != b) ? drow[plist[jb]] + MARGIN : -1e9f;

    float sum = 0.f;
    unsigned int cw = 0;

#define HINGE(TJ, BK)                                       \
    do {                                                    \
        const float v_ = (TJ) - (BK);                       \
        sum += fmaxf(v_, 0.f);                              \
        cw += (unsigned int)__popcll(__ballot(v_ > 0.f));   \
    } while (0)

    if (nneg > 256) {  // uniform rare path
        if (w * 64 < npos) {
#pragma unroll 8
            for (int jj = 0; jj < 64; ++jj) {
                const float tj = __int_as_float(
                    __builtin_amdgcn_readlane(__float_as_int(av0), jj));
                HINGE(tj, bv0); HINGE(tj, bv1);
            }
        }
        if ((w + 4) * 64 < npos) {
#pragma unroll 8
            for (int jj = 0; jj < 64; ++jj) {
                const float tj = __int_as_float(
                    __builtin_amdgcn_readlane(__float_as_int(av1), jj));
                HINGE(tj, bv0); HINGE(tj, bv1);
            }
        }
    } else {  // typical: nneg <= 256
        if (w * 64 < npos) {
#pragma unroll 8
            for (int jj = 0; jj < 64; ++jj) {
                const float tj = __int_as_float(
                    __builtin_amdgcn_readlane(__float_as_int(av0), jj));
                HINGE(tj, bv0);
            }
        }
        if ((w + 4) * 64 < npos) {
#pragma unroll 8
            for (int jj = 0; jj < 64; ++jj) {
                const float tj = __int_as_float(
                    __builtin_amdgcn_readlane(__float_as_int(av1), jj));
                HINGE(tj, bv0);
            }
        }
    }
#undef HINGE

    float wsm = sum;
#pragma unroll
    for (int o = 32; o > 0; o >>= 1) wsm += __shfl_xor(wsm, o, 64);
    if (lane == 0) { sbuf[w] = wsm; cbuf[w] = (float)cw; }
    __syncthreads();
    if (tid == 0) {
        psum[b] = (sbuf[0] + sbuf[1]) + (sbuf[2] + sbuf[3]);
        pcnt[b] = (cbuf[0] + cbuf[1]) + (cbuf[2] + cbuf[3]);
    }
}

// Kernel 3: one wave reduces 512 partial slots + divides. Fixed order.
__global__ __launch_bounds__(64) void kfinal(const float* __restrict__ psum,
                                             const float* __restrict__ pcnt,
                                             float* __restrict__ out) {
    const int lane = threadIdx.x;
    float s = 0.f, c = 0.f;
#pragma unroll
    for (int r = 0; r < 8; ++r) {
        s += psum[r * 64 + lane];
        c += pcnt[r * 64 + lane];
    }
#pragma unroll
    for (int o = 32; o > 0; o >>= 1) {
        s += __shfl_xor(s, o, 64);
        c += __shfl_xor(c, o, 64);
    }
    if (lane == 0) out[0] = s / (c + 1e-7f);
}

extern "C" void kernel_launch(void* const* d_in, const int* in_sizes, int n_in,
                              void* d_out, int out_size, void* d_ws, size_t ws_size,
                              hipStream_t stream) {
    const float* pred = (const float*)d_in[0];
    const int* target = (const int*)d_in[1];
    float* out = (float*)d_out;
    char* base = (char*)d_ws;

    float* dist = (float*)base;                     // 1 MB (pos-space rows)
    float* psum = (float*)(base + 1048576);         // 2 KB
    float* pcnt = (float*)(base + 1050624);         // 2 KB
    int* plist = (int*)(base + 1052672);            // 2 KB
    int* nlist = (int*)(base + 1054720);            // 2 KB
    int* counts = (int*)(base + 1056768);           // 8 B

    // MEASUREMENT ROUND: exact R10 sequence with kdistf and ktriplet each
    // dispatched twice (idempotent rewrites). dur - 26.0 ~= kdistf + ktriplet
    // + 2 boundary gaps -> attributes the unexplained ~15 us.
    ksetup<<<1, 64, 0, stream>>>(target, plist, nlist, counts);
    dim3 gb(16, 16);
    kdistf<<<gb, 64, 0, stream>>>(pred, plist, counts, dist);
    kdistf<<<gb, 64, 0, stream>>>(pred, plist, counts, dist);
    ktriplet<<<512, 256, 0, stream>>>(dist, plist, nlist, counts, psum, pcnt);
    ktriplet<<<512, 256, 0, stream>>>(dist, plist, nlist, counts, psum, pcnt);
    kfinal<<<1, 64, 0, stream>>>(psum, pcnt, out);
}

// Round 17
// 22.025 us; speedup vs baseline: 2.4502x; 1.8093x over previous
//
#include <hip/hip_runtime.h>
#include <hip/hip_bf16.h>

#define BS 512
#define MARGIN 0.5f

using short8 = __attribute__((ext_vector_type(8))) short;
using f32x4 = __attribute__((ext_vector_type(4))) float;

__device__ inline short bf16_rne(float x) {
    __hip_bfloat16 h = __float2bfloat16(x);
    return *(short*)&h;
}

// Kernel 1: compacted-dist. Row space = pos-rank (anchors). Col space =
// [0,npos) pos-rank cols (MARGIN pre-folded), [npos,512) neg-rank cols.
// Each block (1 wave) does its own ballot compaction into LDS (no setup
// kernel). Block (0,0) publishes counts for kernel 2.
__global__ __launch_bounds__(64) void kdistf(const float* __restrict__ pred,
                                             const int* __restrict__ target,
                                             float* __restrict__ dist,
                                             int* __restrict__ counts) {
    const int lane = threadIdx.x;
    __shared__ int plist[BS];
    __shared__ int rnk[BS];
    __shared__ int tgs[BS];

    // one-wave stable compaction: pos-rank / neg-rank per index
    int pbase = 0, nbase = 0;
    const unsigned long long below = (1ULL << lane) - 1ULL;
#pragma unroll
    for (int c = 0; c < 8; ++c) {
        const int idx = c * 64 + lane;
        const int tg = target[idx];
        const unsigned long long mp = __ballot(tg == 1);
        const int prk = pbase + __popcll(mp & below);
        const int nrk = nbase + __popcll((~mp) & below);
        tgs[idx] = tg;
        rnk[idx] = (tg == 1) ? prk : nrk;
        if (tg == 1) plist[prk] = idx;
        const int np = __popcll(mp);
        pbase += np;
        nbase += 64 - np;
    }
    const int npos = pbase;
    __syncthreads();

    if (blockIdx.x == 0 && blockIdx.y == 0 && lane == 0) {
        counts[0] = npos;
        counts[1] = nbase;
    }

    const int r0 = blockIdx.y * 32;
    if (r0 >= npos) return;
    const int c0 = blockIdx.x * 32;
    const int rl = lane & 15;
    const int koff = (lane >> 4) * 8;

    const int pr0 = min(r0 + rl, npos - 1);
    const int pr1 = min(r0 + 16 + rl, npos - 1);
    const float* A0 = pred + plist[pr0] * BS;
    const float* A1 = pred + plist[pr1] * BS;
    const float* B0 = pred + (c0 + rl) * BS;
    const float* B1 = pred + (c0 + 16 + rl) * BS;

    f32x4 acc00 = {0.f, 0.f, 0.f, 0.f};
    f32x4 acc01 = {0.f, 0.f, 0.f, 0.f};
    f32x4 acc10 = {0.f, 0.f, 0.f, 0.f};
    f32x4 acc11 = {0.f, 0.f, 0.f, 0.f};
    float na0 = 0.f, na1 = 0.f, nb0 = 0.f, nb1 = 0.f;

#pragma unroll 4
    for (int ks = 0; ks < 16; ++ks) {
        const int k = ks * 32 + koff;
        const f32x4 a0l = *(const f32x4*)(A0 + k);
        const f32x4 a0h = *(const f32x4*)(A0 + k + 4);
        const f32x4 a1l = *(const f32x4*)(A1 + k);
        const f32x4 a1h = *(const f32x4*)(A1 + k + 4);
        const f32x4 b0l = *(const f32x4*)(B0 + k);
        const f32x4 b0h = *(const f32x4*)(B0 + k + 4);
        const f32x4 b1l = *(const f32x4*)(B1 + k);
        const f32x4 b1h = *(const f32x4*)(B1 + k + 4);

        short8 sa0, sa1, sb0, sb1;
#pragma unroll
        for (int j = 0; j < 4; ++j) {
            na0 += a0l[j] * a0l[j] + a0h[j] * a0h[j];
            na1 += a1l[j] * a1l[j] + a1h[j] * a1h[j];
            nb0 += b0l[j] * b0l[j] + b0h[j] * b0h[j];
            nb1 += b1l[j] * b1l[j] + b1h[j] * b1h[j];
            sa0[j] = bf16_rne(a0l[j]); sa0[4 + j] = bf16_rne(a0h[j]);
            sa1[j] = bf16_rne(a1l[j]); sa1[4 + j] = bf16_rne(a1h[j]);
            sb0[j] = bf16_rne(b0l[j]); sb0[4 + j] = bf16_rne(b0h[j]);
            sb1[j] = bf16_rne(b1l[j]); sb1[4 + j] = bf16_rne(b1h[j]);
        }
        acc00 = __builtin_amdgcn_mfma_f32_16x16x32_bf16(sa0, sb0, acc00, 0, 0, 0);
        acc01 = __builtin_amdgcn_mfma_f32_16x16x32_bf16(sa0, sb1, acc01, 0, 0, 0);
        acc10 = __builtin_amdgcn_mfma_f32_16x16x32_bf16(sa1, sb0, acc10, 0, 0, 0);
        acc11 = __builtin_amdgcn_mfma_f32_16x16x32_bf16(sa1, sb1, acc11, 0, 0, 0);
    }

    na0 += __shfl_xor(na0, 16, 64); na0 += __shfl_xor(na0, 32, 64);
    na1 += __shfl_xor(na1, 16, 64); na1 += __shfl_xor(na1, 32, 64);
    nb0 += __shfl_xor(nb0, 16, 64); nb0 += __shfl_xor(nb0, 32, 64);
    nb1 += __shfl_xor(nb1, 16, 64); nb1 += __shfl_xor(nb1, 32, 64);
    const float ia0 = 1.0f / fmaxf(sqrtf(na0), 1e-10f);
    const float ia1 = 1.0f / fmaxf(sqrtf(na1), 1e-10f);
    const float ib0 = 1.0f / fmaxf(sqrtf(nb0), 1e-10f);
    const float ib1 = 1.0f / fmaxf(sqrtf(nb1), 1e-10f);

    // C/D layout: col = lane&15, row = (lane>>4)*4 + reg  [m89]
    const int rbase = (lane >> 4) * 4;
#pragma unroll
    for (int fr = 0; fr < 2; ++fr) {
        const float iaSel = (fr == 0) ? ia0 : ia1;
#pragma unroll
        for (int fc = 0; fc < 2; ++fc) {
            f32x4 v = (fr == 0) ? (fc == 0 ? acc00 : acc01) : (fc == 0 ? acc10 : acc11);
            const int col = c0 + fc * 16 + rl;
            const float icol = (fc == 0) ? ib0 : ib1;
            const int isPos = tgs[col];
            const int ccol = (isPos == 1) ? rnk[col] : npos + rnk[col];
            const float addM = (isPos == 1) ? MARGIN : 0.0f;
#pragma unroll
            for (int r = 0; r < 4; ++r) {
                const float irow = __shfl(iaSel, rbase + r, 64);
                const int rowp = r0 + fr * 16 + rbase + r;  // pos-rank row
                float d2 = 2.0f - 2.0f * v[r] * irow * icol;
                dist[rowp * BS + ccol] = sqrtf(fmaxf(d2, 0.f)) + addM;
            }
        }
    }
}

// Kernel 2: block b = pos-rank anchor. Pure coalesced loads from compacted
// dist (no index lists, no gathers). j-role cols [0,npos) already have
// MARGIN folded; k-role cols at [npos, npos+nneg). Plain partial stores.
__global__ __launch_bounds__(256) void ktriplet(const float* __restrict__ dist,
                                                const int* __restrict__ counts,
                                                float* __restrict__ psum,
                                                float* __restrict__ pcnt) {
    const int b = blockIdx.x;
    const int tid = threadIdx.x;
    const int npos = counts[0];
    if (b >= npos) {
        if (tid == 0) { psum[b] = 0.f; pcnt[b] = 0.f; }
        return;
    }
    const int nneg = counts[1];
    const int lane = tid & 63;
    const int w = tid >> 6;
    __shared__ float sbuf[4];
    __shared__ float cbuf[4];

    const float* drow = dist + b * BS;

    // k-role: coalesced from [npos + tid]
    const float bv0 = (tid < nneg) ? drow[npos + tid] : 1e30f;
    const float bv1 = (tid + 256 < nneg) ? drow[npos + 256 + tid] : 1e30f;

    // j-role: wave w owns chunks w and w+4; margin already folded
    const int ja = w * 64 + lane;
    const int jb = (w + 4) * 64 + lane;
    const float av0 = (ja < npos && ja != b) ? drow[ja] : -1e9f;
    const float av1 = (jb < npos && jb != b) ? drow[jb] : -1e9f;

    float sum = 0.f;
    unsigned int cw = 0;

#define HINGE(TJ, BK)                                       \
    do {                                                    \
        const float v_ = (TJ) - (BK);                       \
        sum += fmaxf(v_, 0.f);                              \
        cw += (unsigned int)__popcll(__ballot(v_ > 0.f));   \
    } while (0)

    if (nneg > 256) {  // uniform rare path
        if (w * 64 < npos) {
#pragma unroll 8
            for (int jj = 0; jj < 64; ++jj) {
                const float tj = __int_as_float(
                    __builtin_amdgcn_readlane(__float_as_int(av0), jj));
                HINGE(tj, bv0); HINGE(tj, bv1);
            }
        }
        if ((w + 4) * 64 < npos) {
#pragma unroll 8
            for (int jj = 0; jj < 64; ++jj) {
                const float tj = __int_as_float(
                    __builtin_amdgcn_readlane(__float_as_int(av1), jj));
                HINGE(tj, bv0); HINGE(tj, bv1);
            }
        }
    } else {  // typical: nneg <= 256
        if (w * 64 < npos) {
#pragma unroll 8
            for (int jj = 0; jj < 64; ++jj) {
                const float tj = __int_as_float(
                    __builtin_amdgcn_readlane(__float_as_int(av0), jj));
                HINGE(tj, bv0);
            }
        }
        if ((w + 4) * 64 < npos) {
#pragma unroll 8
            for (int jj = 0; jj < 64; ++jj) {
                const float tj = __int_as_float(
                    __builtin_amdgcn_readlane(__float_as_int(av1), jj));
                HINGE(tj, bv0);
            }
        }
    }
#undef HINGE

    float wsm = sum;
#pragma unroll
    for (int o = 32; o > 0; o >>= 1) wsm += __shfl_xor(wsm, o, 64);
    if (lane == 0) { sbuf[w] = wsm; cbuf[w] = (float)cw; }
    __syncthreads();
    if (tid == 0) {
        psum[b] = (sbuf[0] + sbuf[1]) + (sbuf[2] + sbuf[3]);
        pcnt[b] = (cbuf[0] + cbuf[1]) + (cbuf[2] + cbuf[3]);
    }
}

// Kernel 3: one wave reduces 512 partial slots + divides. Fixed order.
__global__ __launch_bounds__(64) void kfinal(const float* __restrict__ psum,
                                             const float* __restrict__ pcnt,
                                             float* __restrict__ out) {
    const int lane = threadIdx.x;
    float s = 0.f, c = 0.f;
#pragma unroll
    for (int r = 0; r < 8; ++r) {
        s += psum[r * 64 + lane];
        c += pcnt[r * 64 + lane];
    }
#pragma unroll
    for (int o = 32; o > 0; o >>= 1) {
        s += __shfl_xor(s, o, 64);
        c += __shfl_xor(c, o, 64);
    }
    if (lane == 0) out[0] = s / (c + 1e-7f);
}

extern "C" void kernel_launch(void* const* d_in, const int* in_sizes, int n_in,
                              void* d_out, int out_size, void* d_ws, size_t ws_size,
                              hipStream_t stream) {
    const float* pred = (const float*)d_in[0];
    const int* target = (const int*)d_in[1];
    float* out = (float*)d_out;
    char* base = (char*)d_ws;

    float* dist = (float*)base;                     // 1 MB (compacted both axes)
    float* psum = (float*)(base + 1048576);         // 2 KB
    float* pcnt = (float*)(base + 1050624);         // 2 KB
    int* counts = (int*)(base + 1052672);           // 8 B

    dim3 gb(16, 16);
    kdistf<<<gb, 64, 0, stream>>>(pred, target, dist, counts);
    ktriplet<<<512, 256, 0, stream>>>(dist, counts, psum, pcnt);
    kfinal<<<1, 64, 0, stream>>>(psum, pcnt, out);
}